// Round 1
// baseline (2557.163 us; speedup 1.0000x reference)
//
#include <hip/hip_runtime.h>
#include <hip/hip_bf16.h>

#define T_TOK 8192
#define DMODEL 1024
#define HDIM 684
#define NEXP 8
#define NPAIR (T_TOK * 2)

// ---------------- workspace layout (bytes) ----------------
// 0      float probs_sum[8]
// 32     int   top1cnt[8]
// 64     int   pair_count[8]
// 96     int   offsets[8]
// 128    int   cursor[8]
// 256    int   topk_idx[T*2]     (64 KiB)
// 65792  float topk_p[T*2]       (64 KiB)
// 131328 int   pair_token[16384] (64 KiB)
// 196864 float pair_prob[16384]  (64 KiB)
// 262656 bf16  h[16384*684]      (~21.4 MiB)

__device__ inline float bf16u_to_f(unsigned short u) {
    return __uint_as_float(((unsigned int)u) << 16);
}

// ---------------- 1. router: softmax + top-2 + aux sums ----------------
__global__ __launch_bounds__(256) void moe_router(
    const float* __restrict__ x, const float* __restrict__ rw,
    float* probs_sum, int* top1cnt, int* pair_count,
    int* topk_idx, float* topk_p)
{
    int lane = threadIdx.x & 63;
    int w    = threadIdx.x >> 6;
    int t    = blockIdx.x * 4 + w;          // grid = 2048 blocks, 4 tokens/block
    const float* xr = x + (size_t)t * DMODEL;

    float acc[NEXP];
#pragma unroll
    for (int e = 0; e < NEXP; ++e) acc[e] = 0.f;
#pragma unroll
    for (int j = 0; j < DMODEL / 64; ++j) {
        float xv = xr[j * 64 + lane];
#pragma unroll
        for (int e = 0; e < NEXP; ++e)
            acc[e] += xv * rw[e * DMODEL + j * 64 + lane];
    }
#pragma unroll
    for (int off = 32; off > 0; off >>= 1) {
#pragma unroll
        for (int e = 0; e < NEXP; ++e)
            acc[e] += __shfl_xor(acc[e], off, 64);
    }
    if (lane == 0) {
        float m = acc[0];
#pragma unroll
        for (int e = 1; e < NEXP; ++e) m = fmaxf(m, acc[e]);
        float p[NEXP];
        float s = 0.f;
#pragma unroll
        for (int e = 0; e < NEXP; ++e) { p[e] = expf(acc[e] - m); s += p[e]; }
        float inv = 1.f / s;
#pragma unroll
        for (int e = 0; e < NEXP; ++e) p[e] *= inv;
        // top-2 (strict > keeps lowest index on ties, matching lax.top_k)
        int i1 = 0;
#pragma unroll
        for (int e = 1; e < NEXP; ++e) if (p[e] > p[i1]) i1 = e;
        int i2 = (i1 == 0) ? 1 : 0;
#pragma unroll
        for (int e = 0; e < NEXP; ++e) if (e != i1 && p[e] > p[i2]) i2 = e;

        topk_idx[t * 2 + 0] = i1;
        topk_idx[t * 2 + 1] = i2;
        topk_p[t * 2 + 0] = p[i1];
        topk_p[t * 2 + 1] = p[i2];
#pragma unroll
        for (int e = 0; e < NEXP; ++e) atomicAdd(&probs_sum[e], p[e]);
        atomicAdd(&top1cnt[i1], 1);
        atomicAdd(&pair_count[i1], 1);
        atomicAdd(&pair_count[i2], 1);
    }
}

// ---------------- 2. prefix scan + aux loss ----------------
__global__ void moe_scan(const float* probs_sum, const int* top1cnt,
                         const int* pair_count, int* offsets, int* cursor,
                         float* aux_out)
{
    if (threadIdx.x == 0) {
        int run = 0;
        for (int e = 0; e < NEXP; ++e) {
            offsets[e] = run; cursor[e] = run; run += pair_count[e];
        }
        float s = 0.f;
        for (int e = 0; e < NEXP; ++e)
            s += ((float)top1cnt[e] / (float)T_TOK) * (probs_sum[e] / (float)T_TOK);
        aux_out[0] = 0.01f * s * (float)NEXP;
    }
}

// ---------------- 3. scatter token ids into per-expert compact lists ----------------
__global__ __launch_bounds__(256) void moe_scatter(
    const int* __restrict__ topk_idx, const float* __restrict__ topk_p,
    int* cursor, int* pair_token, float* pair_prob)
{
    int t = blockIdx.x * 256 + threadIdx.x;
#pragma unroll
    for (int s = 0; s < 2; ++s) {
        int e = topk_idx[t * 2 + s];
        int pos = atomicAdd(&cursor[e], 1);
        pair_token[pos] = t;
        pair_prob[pos]  = topk_p[t * 2 + s];
    }
}

// ---------------- 4. grouped GEMM1: h = silu(Xg @ w1^T) * (Xg @ w3^T) ----------------
// grid: x = 11 (H tiles of 64), y = 128 (M tiles of 64), z = 8 (expert)
__global__ __launch_bounds__(256) void moe_ffn1(
    const float* __restrict__ x, const float* __restrict__ w1,
    const float* __restrict__ w3,
    const int* __restrict__ pair_count, const int* __restrict__ offsets,
    const int* __restrict__ pair_token,
    __hip_bfloat16* __restrict__ h)
{
    int e   = blockIdx.z;
    int cnt = pair_count[e];
    int m0  = blockIdx.y * 64;
    if (m0 >= cnt) return;
    int base = offsets[e];
    int n0   = blockIdx.x * 64;

    __shared__ float aT[16][68];   // [k][row], pad 68 -> conflict-free
    __shared__ float b1T[16][68];
    __shared__ float b3T[16][68];

    int tid = threadIdx.x;
    int tx = tid & 15, ty = tid >> 4;
    int lr = tid >> 2;            // staging row 0..63
    int lk = (tid & 3) * 4;       // staging k offset 0,4,8,12

    int arow = m0 + lr;
    bool avalid = arow < cnt;
    int tok = avalid ? pair_token[base + arow] : 0;
    const float* aptr = x + (size_t)tok * DMODEL + lk;

    int bn = n0 + lr;
    bool bvalid = bn < HDIM;
    const float* b1ptr = w1 + ((size_t)e * HDIM + (bvalid ? bn : 0)) * DMODEL + lk;
    const float* b3ptr = w3 + ((size_t)e * HDIM + (bvalid ? bn : 0)) * DMODEL + lk;

    float acc1[4][4] = {{0}}, acc3[4][4] = {{0}};
    const float4 z4 = make_float4(0.f, 0.f, 0.f, 0.f);

    for (int k0 = 0; k0 < DMODEL; k0 += 16) {
        float4 av  = avalid ? *(const float4*)(aptr + k0)  : z4;
        float4 b1v = bvalid ? *(const float4*)(b1ptr + k0) : z4;
        float4 b3v = bvalid ? *(const float4*)(b3ptr + k0) : z4;
        __syncthreads();
        aT[lk + 0][lr] = av.x;  aT[lk + 1][lr] = av.y;
        aT[lk + 2][lr] = av.z;  aT[lk + 3][lr] = av.w;
        b1T[lk + 0][lr] = b1v.x; b1T[lk + 1][lr] = b1v.y;
        b1T[lk + 2][lr] = b1v.z; b1T[lk + 3][lr] = b1v.w;
        b3T[lk + 0][lr] = b3v.x; b3T[lk + 1][lr] = b3v.y;
        b3T[lk + 2][lr] = b3v.z; b3T[lk + 3][lr] = b3v.w;
        __syncthreads();
#pragma unroll
        for (int kk = 0; kk < 16; ++kk) {
            float4 a  = *(const float4*)&aT[kk][ty * 4];
            float4 b1 = *(const float4*)&b1T[kk][tx * 4];
            float4 b3 = *(const float4*)&b3T[kk][tx * 4];
            float ar[4]  = {a.x, a.y, a.z, a.w};
            float b1r[4] = {b1.x, b1.y, b1.z, b1.w};
            float b3r[4] = {b3.x, b3.y, b3.z, b3.w};
#pragma unroll
            for (int i = 0; i < 4; ++i)
#pragma unroll
                for (int j = 0; j < 4; ++j) {
                    acc1[i][j] += ar[i] * b1r[j];
                    acc3[i][j] += ar[i] * b3r[j];
                }
        }
    }
#pragma unroll
    for (int i = 0; i < 4; ++i) {
        int r = m0 + ty * 4 + i;
        if (r >= cnt) continue;
        size_t hrow = (size_t)(base + r) * HDIM;
#pragma unroll
        for (int j = 0; j < 4; ++j) {
            int c = n0 + tx * 4 + j;
            if (c >= HDIM) continue;
            float v1 = acc1[i][j];
            float hv = (v1 / (1.f + expf(-v1))) * acc3[i][j];
            h[hrow + c] = __float2bfloat16(hv);
        }
    }
}

// ---------------- 5. grouped GEMM2: out[tok] += p * (h @ w2^T) ----------------
// grid: x = 16 (D tiles of 64), y = 128 (M tiles), z = 8 (expert)
__global__ __launch_bounds__(256) void moe_ffn2(
    const __hip_bfloat16* __restrict__ h, const float* __restrict__ w2,
    const int* __restrict__ pair_count, const int* __restrict__ offsets,
    const int* __restrict__ pair_token, const float* __restrict__ pair_prob,
    float* __restrict__ out)
{
    int e   = blockIdx.z;
    int cnt = pair_count[e];
    int m0  = blockIdx.y * 64;
    if (m0 >= cnt) return;
    int base = offsets[e];
    int n0   = blockIdx.x * 64;

    __shared__ float aT[16][68];
    __shared__ float bT[16][68];

    int tid = threadIdx.x;
    int tx = tid & 15, ty = tid >> 4;
    int lr = tid >> 2;
    int lk = (tid & 3) * 4;

    int arow = m0 + lr;
    bool avalid = arow < cnt;
    const __hip_bfloat16* aptr =
        h + (size_t)(base + (avalid ? arow : 0)) * HDIM + lk;

    int bn = n0 + lr;   // < 1024 always
    const float* bptr = w2 + ((size_t)e * DMODEL + bn) * HDIM + lk;

    float acc[4][4] = {{0}};
    const float4 z4 = make_float4(0.f, 0.f, 0.f, 0.f);

    for (int k0 = 0; k0 < 688; k0 += 16) {      // 684 padded to 688
        bool kvalid = (k0 + lk) < HDIM;         // 684 % 4 == 0: granule all-or-none
        float4 bv = kvalid ? *(const float4*)(bptr + k0) : z4;
        float a0 = 0.f, a1 = 0.f, a2 = 0.f, a3 = 0.f;
        if (avalid && kvalid) {
            ushort4 hv = *(const ushort4*)(aptr + k0);
            a0 = bf16u_to_f(hv.x); a1 = bf16u_to_f(hv.y);
            a2 = bf16u_to_f(hv.z); a3 = bf16u_to_f(hv.w);
        }
        __syncthreads();
        aT[lk + 0][lr] = a0;   aT[lk + 1][lr] = a1;
        aT[lk + 2][lr] = a2;   aT[lk + 3][lr] = a3;
        bT[lk + 0][lr] = bv.x; bT[lk + 1][lr] = bv.y;
        bT[lk + 2][lr] = bv.z; bT[lk + 3][lr] = bv.w;
        __syncthreads();
#pragma unroll
        for (int kk = 0; kk < 16; ++kk) {
            float4 a = *(const float4*)&aT[kk][ty * 4];
            float4 b = *(const float4*)&bT[kk][tx * 4];
            float ar[4] = {a.x, a.y, a.z, a.w};
            float br[4] = {b.x, b.y, b.z, b.w};
#pragma unroll
            for (int i = 0; i < 4; ++i)
#pragma unroll
                for (int j = 0; j < 4; ++j)
                    acc[i][j] += ar[i] * br[j];
        }
    }
#pragma unroll
    for (int i = 0; i < 4; ++i) {
        int r = m0 + ty * 4 + i;
        if (r >= cnt) continue;
        int gp = base + r;
        float pw = pair_prob[gp];
        int tok  = pair_token[gp];
        float* orow = out + (size_t)tok * DMODEL + n0 + tx * 4;
#pragma unroll
        for (int j = 0; j < 4; ++j)
            atomicAdd(&orow[j], pw * acc[i][j]);
    }
}

// ---------------- launch ----------------
extern "C" void kernel_launch(void* const* d_in, const int* in_sizes, int n_in,
                              void* d_out, int out_size, void* d_ws, size_t ws_size,
                              hipStream_t stream)
{
    const float* x  = (const float*)d_in[0];
    const float* rw = (const float*)d_in[1];
    const float* w1 = (const float*)d_in[2];
    const float* w2 = (const float*)d_in[3];
    const float* w3 = (const float*)d_in[4];
    float* out = (float*)d_out;

    char* ws = (char*)d_ws;
    float* probs_sum = (float*)(ws + 0);
    int*   top1cnt   = (int*)(ws + 32);
    int*   pair_count= (int*)(ws + 64);
    int*   offsets   = (int*)(ws + 96);
    int*   cursor    = (int*)(ws + 128);
    int*   topk_idx  = (int*)(ws + 256);
    float* topk_p    = (float*)(ws + 65792);
    int*   pair_token= (int*)(ws + 131328);
    float* pair_prob = (float*)(ws + 196864);
    __hip_bfloat16* h = (__hip_bfloat16*)(ws + 262656);

    // out is re-poisoned to 0xAA before every timed launch: zero it (ffn2 atomically
    // accumulates). Zero only the 256-byte counter block of ws; everything else is
    // fully overwritten before being read.
    hipMemsetAsync(d_out, 0, (size_t)out_size * sizeof(float), stream);
    hipMemsetAsync(d_ws, 0, 256, stream);

    moe_router <<<T_TOK / 4, 256, 0, stream>>>(x, rw, probs_sum, top1cnt,
                                               pair_count, topk_idx, topk_p);
    moe_scan   <<<1, 64, 0, stream>>>(probs_sum, top1cnt, pair_count,
                                      offsets, cursor, out + (size_t)T_TOK * DMODEL);
    moe_scatter<<<T_TOK / 256, 256, 0, stream>>>(topk_idx, topk_p, cursor,
                                                 pair_token, pair_prob);
    moe_ffn1   <<<dim3(11, 128, 8), 256, 0, stream>>>(x, w1, w3, pair_count,
                                                      offsets, pair_token, h);
    moe_ffn2   <<<dim3(16, 128, 8), 256, 0, stream>>>(h, w2, pair_count, offsets,
                                                      pair_token, pair_prob, out);
}

// Round 2
// 439.902 us; speedup vs baseline: 5.8130x; 5.8130x over previous
//
#include <hip/hip_runtime.h>
#include <hip/hip_bf16.h>

#define T_TOK 8192
#define DMODEL 1024
#define HDIM 684
#define HPAD 704            // K of GEMM2 padded to a multiple of 32
#define NEXP 8

typedef short  bf16x8  __attribute__((ext_vector_type(8)));   // MFMA A/B frag (8 bf16)
typedef float  f32x4   __attribute__((ext_vector_type(4)));   // MFMA C/D frag
typedef unsigned short ushort8 __attribute__((ext_vector_type(8)));

__device__ inline unsigned short f2bu(float f) {
    __hip_bfloat16 h = __float2bfloat16(f);   // RNE
    return *reinterpret_cast<unsigned short*>(&h);
}

// ---------------- workspace layout (bytes) ----------------
// 0        scalars: pair_count[8]@0, offsets[8]@32, cursor[8]@64
// 256      blk_psum f32[2048*8]
// 65792    blk_t1   i32[2048*8]
// 131328   blk_pc   i32[2048*8]
// 196864   topk_idx i32[16384]
// 262400   topk_p   f32[16384]
// 327936   pair_token i32[16384]
// 393472   pair_prob  f32[16384]
// 459264   xb  bf16[8192*1024]      (16.8 MB)
// 17236480 w1b bf16[8*684*1024]     (11.2 MB)
// 28443136 w3b bf16[8*684*1024]     (11.2 MB)
// 39649792 w2b bf16[8*1024*704]     (11.5 MB, K padded+zeroed)
// 51184128 h   bf16[16384*704]      (23.1 MB, cols 684..703 zeroed by ffn1)

// ---------------- conversions ----------------
__global__ __launch_bounds__(256) void cvt_bf16x4(
    const float* __restrict__ src, unsigned short* __restrict__ dst, int n4)
{
    int i = blockIdx.x * 256 + threadIdx.x;
    if (i >= n4) return;
    float4 v = ((const float4*)src)[i];
    ushort4 o = make_ushort4(f2bu(v.x), f2bu(v.y), f2bu(v.z), f2bu(v.w));
    ((ushort4*)dst)[i] = o;
}

__global__ __launch_bounds__(256) void cvt_w2_pad(
    const float* __restrict__ w2, unsigned short* __restrict__ w2b, int n)
{
    int i = blockIdx.x * 256 + threadIdx.x;       // over 8192 rows * 176 col4
    if (i >= n) return;
    int row = i / 176;
    int col = (i - row * 176) * 4;
    ushort4 o = make_ushort4(0, 0, 0, 0);
    if (col < HDIM) {
        float4 v = *(const float4*)(w2 + (size_t)row * HDIM + col);
        o = make_ushort4(f2bu(v.x), f2bu(v.y), f2bu(v.z), f2bu(v.w));
    }
    *(ushort4*)(w2b + (size_t)row * HPAD + col) = o;
}

// ---------------- 1. router: softmax + top-2, block-local aggregation ----------------
__global__ __launch_bounds__(256) void moe_router(
    const float* __restrict__ x, const float* __restrict__ rw,
    float* __restrict__ blk_psum, int* __restrict__ blk_t1, int* __restrict__ blk_pc,
    int* __restrict__ topk_idx, float* __restrict__ topk_p)
{
    __shared__ float sp[4][NEXP];
    __shared__ int   si1[4], si2[4];

    int lane = threadIdx.x & 63;
    int w    = threadIdx.x >> 6;
    int t    = blockIdx.x * 4 + w;
    const float* xr = x + (size_t)t * DMODEL;

    float acc[NEXP];
#pragma unroll
    for (int e = 0; e < NEXP; ++e) acc[e] = 0.f;
#pragma unroll
    for (int j = 0; j < DMODEL / 64; ++j) {
        float xv = xr[j * 64 + lane];
#pragma unroll
        for (int e = 0; e < NEXP; ++e)
            acc[e] += xv * rw[e * DMODEL + j * 64 + lane];
    }
#pragma unroll
    for (int off = 32; off > 0; off >>= 1) {
#pragma unroll
        for (int e = 0; e < NEXP; ++e)
            acc[e] += __shfl_xor(acc[e], off, 64);
    }
    if (lane == 0) {
        float m = acc[0];
#pragma unroll
        for (int e = 1; e < NEXP; ++e) m = fmaxf(m, acc[e]);
        float p[NEXP]; float s = 0.f;
#pragma unroll
        for (int e = 0; e < NEXP; ++e) { p[e] = expf(acc[e] - m); s += p[e]; }
        float inv = 1.f / s;
#pragma unroll
        for (int e = 0; e < NEXP; ++e) p[e] *= inv;
        int i1 = 0;
#pragma unroll
        for (int e = 1; e < NEXP; ++e) if (p[e] > p[i1]) i1 = e;
        int i2 = (i1 == 0) ? 1 : 0;
#pragma unroll
        for (int e = 0; e < NEXP; ++e) if (e != i1 && p[e] > p[i2]) i2 = e;

        topk_idx[t * 2 + 0] = i1;  topk_idx[t * 2 + 1] = i2;
        topk_p[t * 2 + 0] = p[i1]; topk_p[t * 2 + 1] = p[i2];
#pragma unroll
        for (int e = 0; e < NEXP; ++e) sp[w][e] = p[e];
        si1[w] = i1; si2[w] = i2;
    }
    __syncthreads();
    if (threadIdx.x < NEXP) {
        int e = threadIdx.x;
        float ps = sp[0][e] + sp[1][e] + sp[2][e] + sp[3][e];
        int t1 = (si1[0] == e) + (si1[1] == e) + (si1[2] == e) + (si1[3] == e);
        int pc = t1 + (si2[0] == e) + (si2[1] == e) + (si2[2] == e) + (si2[3] == e);
        blk_psum[blockIdx.x * NEXP + e] = ps;
        blk_t1[blockIdx.x * NEXP + e]  = t1;
        blk_pc[blockIdx.x * NEXP + e]  = pc;
    }
}

// ---------------- 2. scan: totals, offsets, aux ----------------
__global__ __launch_bounds__(256) void moe_scan(
    const float* __restrict__ blk_psum, const int* __restrict__ blk_t1,
    const int* __restrict__ blk_pc,
    int* pair_count, int* offsets, int* cursor, float* aux_out)
{
    __shared__ float rp[256][NEXP];
    __shared__ int   rt[256][NEXP], rc[256][NEXP];
    __shared__ float tp[NEXP];
    __shared__ int   tt1[NEXP], tpc[NEXP];

    int tid = threadIdx.x;
    float lp[NEXP]; int lt[NEXP], lc[NEXP];
#pragma unroll
    for (int e = 0; e < NEXP; ++e) { lp[e] = 0.f; lt[e] = 0; lc[e] = 0; }
    for (int b = tid; b < 2048; b += 256)
#pragma unroll
        for (int e = 0; e < NEXP; ++e) {
            lp[e] += blk_psum[b * NEXP + e];
            lt[e] += blk_t1[b * NEXP + e];
            lc[e] += blk_pc[b * NEXP + e];
        }
#pragma unroll
    for (int e = 0; e < NEXP; ++e) { rp[tid][e] = lp[e]; rt[tid][e] = lt[e]; rc[tid][e] = lc[e]; }
    __syncthreads();
    if (tid < NEXP) {
        float s = 0.f; int t1 = 0, pc = 0;
        for (int i = 0; i < 256; ++i) { s += rp[i][tid]; t1 += rt[i][tid]; pc += rc[i][tid]; }
        tp[tid] = s; tt1[tid] = t1; tpc[tid] = pc;
        pair_count[tid] = pc;
    }
    __syncthreads();
    if (tid == 0) {
        int run = 0;
        for (int e = 0; e < NEXP; ++e) { offsets[e] = run; cursor[e] = run; run += tpc[e]; }
        float s = 0.f;
        for (int e = 0; e < NEXP; ++e)
            s += ((float)tt1[e] / (float)T_TOK) * (tp[e] / (float)T_TOK);
        aux_out[0] = 0.01f * s * (float)NEXP;
    }
}

// ---------------- 3. scatter (block-aggregated cursor atomics) ----------------
__global__ __launch_bounds__(256) void moe_scatter(
    const int* __restrict__ topk_idx, const float* __restrict__ topk_p,
    int* cursor, int* __restrict__ pair_token, float* __restrict__ pair_prob)
{
    __shared__ int lcnt[NEXP], gbase[NEXP];
    int tid = threadIdx.x;
    if (tid < NEXP) lcnt[tid] = 0;
    __syncthreads();
    int t = blockIdx.x * 256 + tid;
    int e0 = topk_idx[t * 2 + 0], e1 = topk_idx[t * 2 + 1];
    int p0 = atomicAdd(&lcnt[e0], 1);
    int p1 = atomicAdd(&lcnt[e1], 1);
    __syncthreads();
    if (tid < NEXP) gbase[tid] = atomicAdd(&cursor[tid], lcnt[tid]);
    __syncthreads();
    int q0 = gbase[e0] + p0, q1 = gbase[e1] + p1;
    pair_token[q0] = t; pair_prob[q0] = topk_p[t * 2 + 0];
    pair_token[q1] = t; pair_prob[q1] = topk_p[t * 2 + 1];
}

// ---------------- 4. MFMA GEMM1: h = silu(Xg w1^T) * (Xg w3^T) ----------------
// grid (6, 64, 8); block 256 = 4 waves; 128x128 tile, BK=32
__global__ __launch_bounds__(256) void moe_ffn1(
    const unsigned short* __restrict__ xb, const unsigned short* __restrict__ w1b,
    const unsigned short* __restrict__ w3b,
    const int* __restrict__ pair_count, const int* __restrict__ offsets,
    const int* __restrict__ pair_token,
    unsigned short* __restrict__ h)
{
    int e   = blockIdx.z;
    int cnt = pair_count[e];
    int m0  = blockIdx.y * 128;
    if (m0 >= cnt) return;
    int base = offsets[e];
    int n0   = blockIdx.x * 128;

    __shared__ unsigned short aT[128][40];   // stride 40 -> <=2-way banks (free)
    __shared__ unsigned short b1T[128][40];
    __shared__ unsigned short b3T[128][40];

    int tid  = threadIdx.x;
    int lane = tid & 63, wave = tid >> 6;
    int wm = wave >> 1, wn = wave & 1;

    // staging: thread -> (row tid>>1, k-half (tid&1)*16)
    int srow = tid >> 1;
    int kh   = (tid & 1) * 16;
    int grow = m0 + srow;
    int tok  = pair_token[base + (grow < cnt ? grow : cnt - 1)];
    const unsigned short* ap  = xb + (size_t)tok * DMODEL + kh;
    int nrow = n0 + srow; if (nrow > HDIM - 1) nrow = HDIM - 1;
    const unsigned short* b1p = w1b + ((size_t)e * HDIM + nrow) * DMODEL + kh;
    const unsigned short* b3p = w3b + ((size_t)e * HDIM + nrow) * DMODEL + kh;

    f32x4 acc1[4][4], acc3[4][4];
#pragma unroll
    for (int i = 0; i < 4; ++i)
#pragma unroll
        for (int j = 0; j < 4; ++j) {
            acc1[i][j] = (f32x4)(0.f);
            acc3[i][j] = (f32x4)(0.f);
        }

    int fr = lane & 15, fk = (lane >> 4) * 8;

    for (int k0 = 0; k0 < DMODEL; k0 += 32) {
        ushort8 av0 = *(const ushort8*)(ap + k0);
        ushort8 av1 = *(const ushort8*)(ap + k0 + 8);
        ushort8 b10 = *(const ushort8*)(b1p + k0);
        ushort8 b11 = *(const ushort8*)(b1p + k0 + 8);
        ushort8 b30 = *(const ushort8*)(b3p + k0);
        ushort8 b31 = *(const ushort8*)(b3p + k0 + 8);
        __syncthreads();
        *(ushort8*)&aT[srow][kh]      = av0;
        *(ushort8*)&aT[srow][kh + 8]  = av1;
        *(ushort8*)&b1T[srow][kh]     = b10;
        *(ushort8*)&b1T[srow][kh + 8] = b11;
        *(ushort8*)&b3T[srow][kh]     = b30;
        *(ushort8*)&b3T[srow][kh + 8] = b31;
        __syncthreads();

        bf16x8 aF[4];
#pragma unroll
        for (int i = 0; i < 4; ++i)
            aF[i] = *(const bf16x8*)&aT[wm * 64 + i * 16 + fr][fk];
#pragma unroll
        for (int j = 0; j < 4; ++j) {
            bf16x8 b1F = *(const bf16x8*)&b1T[wn * 64 + j * 16 + fr][fk];
            bf16x8 b3F = *(const bf16x8*)&b3T[wn * 64 + j * 16 + fr][fk];
#pragma unroll
            for (int i = 0; i < 4; ++i) {
                acc1[i][j] = __builtin_amdgcn_mfma_f32_16x16x32_bf16(aF[i], b1F, acc1[i][j], 0, 0, 0);
                acc3[i][j] = __builtin_amdgcn_mfma_f32_16x16x32_bf16(aF[i], b3F, acc3[i][j], 0, 0, 0);
            }
        }
    }

    // epilogue: C/D layout col=lane&15, row=(lane>>4)*4+reg
    int cbase = n0 + wn * 64 + (lane & 15);
    int rbase = m0 + wm * 64 + (lane >> 4) * 4;
#pragma unroll
    for (int i = 0; i < 4; ++i) {
#pragma unroll
        for (int r = 0; r < 4; ++r) {
            int gr = rbase + i * 16 + r;
            if (gr >= cnt) continue;
            unsigned short* hrow = h + (size_t)(base + gr) * HPAD;
#pragma unroll
            for (int j = 0; j < 4; ++j) {
                int col = cbase + j * 16;
                if (col >= HPAD) continue;
                float v1 = acc1[i][j][r];
                float hv = (col < HDIM) ? (v1 / (1.f + expf(-v1))) * acc3[i][j][r] : 0.f;
                hrow[col] = f2bu(hv);
            }
        }
    }
}

// ---------------- 5. MFMA GEMM2: out[tok] += p * (h w2^T) ----------------
// grid (8, 64, 8); K = 704 (zero-padded)
__global__ __launch_bounds__(256) void moe_ffn2(
    const unsigned short* __restrict__ h, const unsigned short* __restrict__ w2b,
    const int* __restrict__ pair_count, const int* __restrict__ offsets,
    const int* __restrict__ pair_token, const float* __restrict__ pair_prob,
    float* __restrict__ out)
{
    int e   = blockIdx.z;
    int cnt = pair_count[e];
    int m0  = blockIdx.y * 128;
    if (m0 >= cnt) return;
    int base = offsets[e];
    int n0   = blockIdx.x * 128;

    __shared__ unsigned short aT[128][40];
    __shared__ unsigned short bT[128][40];

    int tid  = threadIdx.x;
    int lane = tid & 63, wave = tid >> 6;
    int wm = wave >> 1, wn = wave & 1;

    int srow = tid >> 1;
    int kh   = (tid & 1) * 16;
    int grow = m0 + srow;
    const unsigned short* ap = h + (size_t)(base + (grow < cnt ? grow : cnt - 1)) * HPAD + kh;
    const unsigned short* bp = w2b + ((size_t)e * DMODEL + n0 + srow) * HPAD + kh;

    f32x4 acc[4][4];
#pragma unroll
    for (int i = 0; i < 4; ++i)
#pragma unroll
        for (int j = 0; j < 4; ++j) acc[i][j] = (f32x4)(0.f);

    int fr = lane & 15, fk = (lane >> 4) * 8;

    for (int k0 = 0; k0 < HPAD; k0 += 32) {
        ushort8 av0 = *(const ushort8*)(ap + k0);
        ushort8 av1 = *(const ushort8*)(ap + k0 + 8);
        ushort8 bv0 = *(const ushort8*)(bp + k0);
        ushort8 bv1 = *(const ushort8*)(bp + k0 + 8);
        __syncthreads();
        *(ushort8*)&aT[srow][kh]     = av0;
        *(ushort8*)&aT[srow][kh + 8] = av1;
        *(ushort8*)&bT[srow][kh]     = bv0;
        *(ushort8*)&bT[srow][kh + 8] = bv1;
        __syncthreads();

        bf16x8 aF[4];
#pragma unroll
        for (int i = 0; i < 4; ++i)
            aF[i] = *(const bf16x8*)&aT[wm * 64 + i * 16 + fr][fk];
#pragma unroll
        for (int j = 0; j < 4; ++j) {
            bf16x8 bF = *(const bf16x8*)&bT[wn * 64 + j * 16 + fr][fk];
#pragma unroll
            for (int i = 0; i < 4; ++i)
                acc[i][j] = __builtin_amdgcn_mfma_f32_16x16x32_bf16(aF[i], bF, acc[i][j], 0, 0, 0);
        }
    }

    int cbase = n0 + wn * 64 + (lane & 15);
    int rbase = m0 + wm * 64 + (lane >> 4) * 4;
#pragma unroll
    for (int i = 0; i < 4; ++i) {
#pragma unroll
        for (int r = 0; r < 4; ++r) {
            int gr = rbase + i * 16 + r;
            if (gr >= cnt) continue;
            int gp = base + gr;
            float pw = pair_prob[gp];
            float* orow = out + (size_t)pair_token[gp] * DMODEL;
#pragma unroll
            for (int j = 0; j < 4; ++j) {
                int col = cbase + j * 16;
                atomicAdd(&orow[col], pw * acc[i][j][r]);
            }
        }
    }
}

// ---------------- launch ----------------
extern "C" void kernel_launch(void* const* d_in, const int* in_sizes, int n_in,
                              void* d_out, int out_size, void* d_ws, size_t ws_size,
                              hipStream_t stream)
{
    const float* x  = (const float*)d_in[0];
    const float* rw = (const float*)d_in[1];
    const float* w1 = (const float*)d_in[2];
    const float* w2 = (const float*)d_in[3];
    const float* w3 = (const float*)d_in[4];
    float* out = (float*)d_out;

    char* ws = (char*)d_ws;
    int*   pair_count = (int*)(ws + 0);
    int*   offsets    = (int*)(ws + 32);
    int*   cursor     = (int*)(ws + 64);
    float* blk_psum   = (float*)(ws + 256);
    int*   blk_t1     = (int*)(ws + 65792);
    int*   blk_pc     = (int*)(ws + 131328);
    int*   topk_idx   = (int*)(ws + 196864);
    float* topk_p     = (float*)(ws + 262400);
    int*   pair_token = (int*)(ws + 327936);
    float* pair_prob  = (float*)(ws + 393472);
    unsigned short* xb  = (unsigned short*)(ws + 459264);
    unsigned short* w1b = (unsigned short*)(ws + 17236480);
    unsigned short* w3b = (unsigned short*)(ws + 28443136);
    unsigned short* w2b = (unsigned short*)(ws + 39649792);
    unsigned short* hbuf= (unsigned short*)(ws + 51184128);

    hipMemsetAsync(d_out, 0, (size_t)out_size * sizeof(float), stream);

    // bf16 conversions (x, w1, w3 dense; w2 K-padded to 704 with zeros)
    cvt_bf16x4<<<(T_TOK * DMODEL / 4 + 255) / 256, 256, 0, stream>>>(x, xb, T_TOK * DMODEL / 4);
    cvt_bf16x4<<<(NEXP * HDIM * DMODEL / 4 + 255) / 256, 256, 0, stream>>>(w1, w1b, NEXP * HDIM * DMODEL / 4);
    cvt_bf16x4<<<(NEXP * HDIM * DMODEL / 4 + 255) / 256, 256, 0, stream>>>(w3, w3b, NEXP * HDIM * DMODEL / 4);
    cvt_w2_pad<<<(NEXP * DMODEL * (HPAD / 4) + 255) / 256, 256, 0, stream>>>(w2, w2b, NEXP * DMODEL * (HPAD / 4));

    moe_router <<<T_TOK / 4, 256, 0, stream>>>(x, rw, blk_psum, blk_t1, blk_pc, topk_idx, topk_p);
    moe_scan   <<<1, 256, 0, stream>>>(blk_psum, blk_t1, blk_pc, pair_count, offsets, cursor,
                                       out + (size_t)T_TOK * DMODEL);
    moe_scatter<<<T_TOK / 256, 256, 0, stream>>>(topk_idx, topk_p, cursor, pair_token, pair_prob);

    moe_ffn1<<<dim3(6, 64, 8), 256, 0, stream>>>(xb, w1b, w3b, pair_count, offsets, pair_token, hbuf);
    moe_ffn2<<<dim3(8, 64, 8), 256, 0, stream>>>(hbuf, w2b, pair_count, offsets, pair_token, pair_prob, out);
}

// Round 3
// 419.861 us; speedup vs baseline: 6.0905x; 1.0477x over previous
//
#include <hip/hip_runtime.h>
#include <hip/hip_bf16.h>

#define T_TOK 8192
#define DMODEL 1024
#define HDIM 684
#define HPAD 704
#define NEXP 8

typedef short  bf16x8  __attribute__((ext_vector_type(8)));
typedef float  f32x4   __attribute__((ext_vector_type(4)));

__device__ inline unsigned short f2bu(float f) {
    __hip_bfloat16 h = __float2bfloat16(f);   // RNE
    return *reinterpret_cast<unsigned short*>(&h);
}

typedef const __attribute__((address_space(1))) unsigned int* gas_p;
typedef __attribute__((address_space(3))) unsigned int* las_p;
__device__ inline void ld_lds16(const unsigned short* g, unsigned short* l) {
    __builtin_amdgcn_global_load_lds((gas_p)g, (las_p)l, 16, 0, 0);
}

// ---------------- workspace layout (bytes) ----------------
// 0        pair_count[8]@0, offsets[8]@32, cursor[8]@64
// 256      blk_psum f32[2048*8]
// 65792    blk_t1   i32[2048*8]
// 131328   blk_pc   i32[2048*8]
// 196864   topk_idx i32[16384]
// 262400   topk_p   f32[16384]
// 327936   pair_token i32[16384]
// 393472   pair_prob  f32[16384]
// 459264   xb  bf16[8192*1024]
// 17236480 w1b bf16[8*684*1024]
// 28443136 w3b bf16[8*684*1024]
// 39649792 w2b bf16[8*1024*704]  (K padded+zeroed)
// 51184128 h   bf16[16384*704]   (cols 684..703 zeroed by ffn1)

// ---------------- conversions ----------------
__global__ __launch_bounds__(256) void cvt_bf16x4(
    const float* __restrict__ src, unsigned short* __restrict__ dst, int n4)
{
    int i = blockIdx.x * 256 + threadIdx.x;
    if (i >= n4) return;
    float4 v = ((const float4*)src)[i];
    ushort4 o = make_ushort4(f2bu(v.x), f2bu(v.y), f2bu(v.z), f2bu(v.w));
    ((ushort4*)dst)[i] = o;
}

__global__ __launch_bounds__(256) void cvt_w2_pad(
    const float* __restrict__ w2, unsigned short* __restrict__ w2b, int n)
{
    int i = blockIdx.x * 256 + threadIdx.x;
    if (i >= n) return;
    int row = i / 176;
    int col = (i - row * 176) * 4;
    ushort4 o = make_ushort4(0, 0, 0, 0);
    if (col < HDIM) {
        float4 v = *(const float4*)(w2 + (size_t)row * HDIM + col);
        o = make_ushort4(f2bu(v.x), f2bu(v.y), f2bu(v.z), f2bu(v.w));
    }
    *(ushort4*)(w2b + (size_t)row * HPAD + col) = o;
}

// ---------------- 1. router (+ fused x->bf16) ----------------
__global__ __launch_bounds__(256) void moe_router(
    const float* __restrict__ x, const float* __restrict__ rw,
    unsigned short* __restrict__ xb,
    float* __restrict__ blk_psum, int* __restrict__ blk_t1, int* __restrict__ blk_pc,
    int* __restrict__ topk_idx, float* __restrict__ topk_p)
{
    __shared__ float sp[4][NEXP];
    __shared__ int   si1[4], si2[4];

    int lane = threadIdx.x & 63;
    int w    = threadIdx.x >> 6;
    int t    = blockIdx.x * 4 + w;
    const float* xr = x + (size_t)t * DMODEL;
    unsigned short* xbr = xb + (size_t)t * DMODEL;

    float acc[NEXP];
#pragma unroll
    for (int e = 0; e < NEXP; ++e) acc[e] = 0.f;
#pragma unroll
    for (int j = 0; j < DMODEL / 64; ++j) {
        float xv = xr[j * 64 + lane];
        xbr[j * 64 + lane] = f2bu(xv);
#pragma unroll
        for (int e = 0; e < NEXP; ++e)
            acc[e] += xv * rw[e * DMODEL + j * 64 + lane];
    }
#pragma unroll
    for (int off = 32; off > 0; off >>= 1) {
#pragma unroll
        for (int e = 0; e < NEXP; ++e)
            acc[e] += __shfl_xor(acc[e], off, 64);
    }
    if (lane == 0) {
        float m = acc[0];
#pragma unroll
        for (int e = 1; e < NEXP; ++e) m = fmaxf(m, acc[e]);
        float p[NEXP]; float s = 0.f;
#pragma unroll
        for (int e = 0; e < NEXP; ++e) { p[e] = expf(acc[e] - m); s += p[e]; }
        float inv = 1.f / s;
#pragma unroll
        for (int e = 0; e < NEXP; ++e) p[e] *= inv;
        int i1 = 0;
#pragma unroll
        for (int e = 1; e < NEXP; ++e) if (p[e] > p[i1]) i1 = e;
        int i2 = (i1 == 0) ? 1 : 0;
#pragma unroll
        for (int e = 0; e < NEXP; ++e) if (e != i1 && p[e] > p[i2]) i2 = e;

        topk_idx[t * 2 + 0] = i1;  topk_idx[t * 2 + 1] = i2;
        topk_p[t * 2 + 0] = p[i1]; topk_p[t * 2 + 1] = p[i2];
#pragma unroll
        for (int e = 0; e < NEXP; ++e) sp[w][e] = p[e];
        si1[w] = i1; si2[w] = i2;
    }
    __syncthreads();
    if (threadIdx.x < NEXP) {
        int e = threadIdx.x;
        float ps = sp[0][e] + sp[1][e] + sp[2][e] + sp[3][e];
        int t1 = (si1[0] == e) + (si1[1] == e) + (si1[2] == e) + (si1[3] == e);
        int pc = t1 + (si2[0] == e) + (si2[1] == e) + (si2[2] == e) + (si2[3] == e);
        blk_psum[blockIdx.x * NEXP + e] = ps;
        blk_t1[blockIdx.x * NEXP + e]  = t1;
        blk_pc[blockIdx.x * NEXP + e]  = pc;
    }
}

// ---------------- 2. scan ----------------
__global__ __launch_bounds__(256) void moe_scan(
    const float* __restrict__ blk_psum, const int* __restrict__ blk_t1,
    const int* __restrict__ blk_pc,
    int* pair_count, int* offsets, int* cursor, float* aux_out)
{
    __shared__ float rp[256][NEXP];
    __shared__ int   rt[256][NEXP], rc[256][NEXP];
    __shared__ float tp[NEXP];
    __shared__ int   tt1[NEXP], tpc[NEXP];

    int tid = threadIdx.x;
    float lp[NEXP]; int lt[NEXP], lc[NEXP];
#pragma unroll
    for (int e = 0; e < NEXP; ++e) { lp[e] = 0.f; lt[e] = 0; lc[e] = 0; }
    for (int b = tid; b < 2048; b += 256)
#pragma unroll
        for (int e = 0; e < NEXP; ++e) {
            lp[e] += blk_psum[b * NEXP + e];
            lt[e] += blk_t1[b * NEXP + e];
            lc[e] += blk_pc[b * NEXP + e];
        }
#pragma unroll
    for (int e = 0; e < NEXP; ++e) { rp[tid][e] = lp[e]; rt[tid][e] = lt[e]; rc[tid][e] = lc[e]; }
    __syncthreads();
    if (tid < NEXP) {
        float s = 0.f; int t1 = 0, pc = 0;
        for (int i = 0; i < 256; ++i) { s += rp[i][tid]; t1 += rt[i][tid]; pc += rc[i][tid]; }
        tp[tid] = s; tt1[tid] = t1; tpc[tid] = pc;
        pair_count[tid] = pc;
    }
    __syncthreads();
    if (tid == 0) {
        int run = 0;
        for (int e = 0; e < NEXP; ++e) { offsets[e] = run; cursor[e] = run; run += tpc[e]; }
        float s = 0.f;
        for (int e = 0; e < NEXP; ++e)
            s += ((float)tt1[e] / (float)T_TOK) * (tp[e] / (float)T_TOK);
        aux_out[0] = 0.01f * s * (float)NEXP;
    }
}

// ---------------- 3. scatter ----------------
__global__ __launch_bounds__(256) void moe_scatter(
    const int* __restrict__ topk_idx, const float* __restrict__ topk_p,
    int* cursor, int* __restrict__ pair_token, float* __restrict__ pair_prob)
{
    __shared__ int lcnt[NEXP], gbase[NEXP];
    int tid = threadIdx.x;
    if (tid < NEXP) lcnt[tid] = 0;
    __syncthreads();
    int t = blockIdx.x * 256 + tid;
    int e0 = topk_idx[t * 2 + 0], e1 = topk_idx[t * 2 + 1];
    int p0 = atomicAdd(&lcnt[e0], 1);
    int p1 = atomicAdd(&lcnt[e1], 1);
    __syncthreads();
    if (tid < NEXP) gbase[tid] = atomicAdd(&cursor[tid], lcnt[tid]);
    __syncthreads();
    int q0 = gbase[e0] + p0, q1 = gbase[e1] + p1;
    pair_token[q0] = t; pair_prob[q0] = topk_p[t * 2 + 0];
    pair_token[q1] = t; pair_prob[q1] = topk_p[t * 2 + 1];
}

// LDS tile: 128 rows x 32 k (bf16), flat 4096 ushorts. 16B granule;
// physical granule for (row,kseg) = row*4 + (kseg ^ (row&3))  [XOR swizzle]
// -> frag ds_read_b128 perfectly bank-balanced; staging is lane-contiguous.

// ---------------- 4. MFMA GEMM1 ----------------
// grid (6, 64, 8); 4 waves; 128x128 tile, BK=32, global_load_lds staging
__global__ __launch_bounds__(256) void moe_ffn1(
    const unsigned short* __restrict__ xb, const unsigned short* __restrict__ w1b,
    const unsigned short* __restrict__ w3b,
    const int* __restrict__ pair_count, const int* __restrict__ offsets,
    const int* __restrict__ pair_token,
    unsigned short* __restrict__ h)
{
    int e   = blockIdx.z;
    int cnt = pair_count[e];
    int m0  = blockIdx.y * 128;
    if (m0 >= cnt) return;
    int base = offsets[e];
    int n0   = blockIdx.x * 128;

    __shared__ unsigned short aT[4096];
    __shared__ unsigned short b1T[4096];
    __shared__ unsigned short b3T[4096];

    int tid  = threadIdx.x;
    int lane = tid & 63, wave = tid >> 6;
    int wm = wave >> 1, wn = wave & 1;

    // staging decomposition: wave stages chunks {2w,2w+1} of each matrix;
    // lane -> row 16c+(lane>>2), logical kseg (lane&3)^((lane>>2)&3)
    int srow = lane >> 2;
    int ksg  = (lane & 3) ^ (srow & 3);
    int c0 = wave * 2, c1 = c0 + 1;

    int ar0 = m0 + c0 * 16 + srow; if (ar0 >= cnt) ar0 = cnt - 1;
    int ar1 = m0 + c1 * 16 + srow; if (ar1 >= cnt) ar1 = cnt - 1;
    const unsigned short* apA0 = xb + (size_t)pair_token[base + ar0] * DMODEL + ksg * 8;
    const unsigned short* apA1 = xb + (size_t)pair_token[base + ar1] * DMODEL + ksg * 8;
    int br0 = n0 + c0 * 16 + srow; if (br0 > HDIM - 1) br0 = HDIM - 1;
    int br1 = n0 + c1 * 16 + srow; if (br1 > HDIM - 1) br1 = HDIM - 1;
    const unsigned short* b1p0 = w1b + ((size_t)e * HDIM + br0) * DMODEL + ksg * 8;
    const unsigned short* b1p1 = w1b + ((size_t)e * HDIM + br1) * DMODEL + ksg * 8;
    const unsigned short* b3p0 = w3b + ((size_t)e * HDIM + br0) * DMODEL + ksg * 8;
    const unsigned short* b3p1 = w3b + ((size_t)e * HDIM + br1) * DMODEL + ksg * 8;
    unsigned short* lA0 = &aT[c0 * 512];  unsigned short* lA1 = &aT[c1 * 512];
    unsigned short* lB10 = &b1T[c0 * 512]; unsigned short* lB11 = &b1T[c1 * 512];
    unsigned short* lB30 = &b3T[c0 * 512]; unsigned short* lB31 = &b3T[c1 * 512];

    f32x4 acc1[4][4], acc3[4][4];
#pragma unroll
    for (int i = 0; i < 4; ++i)
#pragma unroll
        for (int j = 0; j < 4; ++j) { acc1[i][j] = (f32x4)(0.f); acc3[i][j] = (f32x4)(0.f); }

    int fr  = lane & 15;
    int sz8 = (((lane >> 4) ^ (fr & 3))) * 8;   // swizzled kseg offset (ushorts)

    for (int k0 = 0; k0 < DMODEL; k0 += 32) {
        ld_lds16(apA0 + k0, lA0);
        ld_lds16(apA1 + k0, lA1);
        ld_lds16(b1p0 + k0, lB10);
        ld_lds16(b1p1 + k0, lB11);
        ld_lds16(b3p0 + k0, lB30);
        ld_lds16(b3p1 + k0, lB31);
        __syncthreads();

        bf16x8 aF[4];
#pragma unroll
        for (int i = 0; i < 4; ++i)
            aF[i] = *(const bf16x8*)&aT[(wm * 64 + i * 16 + fr) * 32 + sz8];
#pragma unroll
        for (int j = 0; j < 4; ++j) {
            int row = (wn * 64 + j * 16 + fr) * 32 + sz8;
            bf16x8 b1F = *(const bf16x8*)&b1T[row];
            bf16x8 b3F = *(const bf16x8*)&b3T[row];
#pragma unroll
            for (int i = 0; i < 4; ++i) {
                acc1[i][j] = __builtin_amdgcn_mfma_f32_16x16x32_bf16(aF[i], b1F, acc1[i][j], 0, 0, 0);
                acc3[i][j] = __builtin_amdgcn_mfma_f32_16x16x32_bf16(aF[i], b3F, acc3[i][j], 0, 0, 0);
            }
        }
        __syncthreads();
    }

    int cbase = n0 + wn * 64 + fr;
    int rbase = m0 + wm * 64 + (lane >> 4) * 4;
#pragma unroll
    for (int i = 0; i < 4; ++i) {
#pragma unroll
        for (int r = 0; r < 4; ++r) {
            int gr = rbase + i * 16 + r;
            if (gr >= cnt) continue;
            unsigned short* hrow = h + (size_t)(base + gr) * HPAD;
#pragma unroll
            for (int j = 0; j < 4; ++j) {
                int col = cbase + j * 16;
                if (col >= HPAD) continue;
                float v1 = acc1[i][j][r];
                float hv = (col < HDIM) ? (v1 / (1.f + expf(-v1))) * acc3[i][j][r] : 0.f;
                hrow[col] = f2bu(hv);
            }
        }
    }
}

// ---------------- 5. MFMA GEMM2 ----------------
// grid (8, 64, 8); K = 704
__global__ __launch_bounds__(256) void moe_ffn2(
    const unsigned short* __restrict__ h, const unsigned short* __restrict__ w2b,
    const int* __restrict__ pair_count, const int* __restrict__ offsets,
    const int* __restrict__ pair_token, const float* __restrict__ pair_prob,
    float* __restrict__ out)
{
    int e   = blockIdx.z;
    int cnt = pair_count[e];
    int m0  = blockIdx.y * 128;
    if (m0 >= cnt) return;
    int base = offsets[e];
    int n0   = blockIdx.x * 128;

    __shared__ unsigned short aT[4096];
    __shared__ unsigned short bT[4096];

    int tid  = threadIdx.x;
    int lane = tid & 63, wave = tid >> 6;
    int wm = wave >> 1, wn = wave & 1;

    int srow = lane >> 2;
    int ksg  = (lane & 3) ^ (srow & 3);
    int c0 = wave * 2, c1 = c0 + 1;

    int ar0 = m0 + c0 * 16 + srow; if (ar0 >= cnt) ar0 = cnt - 1;
    int ar1 = m0 + c1 * 16 + srow; if (ar1 >= cnt) ar1 = cnt - 1;
    const unsigned short* apA0 = h + (size_t)(base + ar0) * HPAD + ksg * 8;
    const unsigned short* apA1 = h + (size_t)(base + ar1) * HPAD + ksg * 8;
    const unsigned short* bp0 = w2b + ((size_t)e * DMODEL + n0 + c0 * 16 + srow) * HPAD + ksg * 8;
    const unsigned short* bp1 = w2b + ((size_t)e * DMODEL + n0 + c1 * 16 + srow) * HPAD + ksg * 8;
    unsigned short* lA0 = &aT[c0 * 512]; unsigned short* lA1 = &aT[c1 * 512];
    unsigned short* lB0 = &bT[c0 * 512]; unsigned short* lB1 = &bT[c1 * 512];

    f32x4 acc[4][4];
#pragma unroll
    for (int i = 0; i < 4; ++i)
#pragma unroll
        for (int j = 0; j < 4; ++j) acc[i][j] = (f32x4)(0.f);

    int fr  = lane & 15;
    int sz8 = (((lane >> 4) ^ (fr & 3))) * 8;

    for (int k0 = 0; k0 < HPAD; k0 += 32) {
        ld_lds16(apA0 + k0, lA0);
        ld_lds16(apA1 + k0, lA1);
        ld_lds16(bp0 + k0, lB0);
        ld_lds16(bp1 + k0, lB1);
        __syncthreads();

        bf16x8 aF[4];
#pragma unroll
        for (int i = 0; i < 4; ++i)
            aF[i] = *(const bf16x8*)&aT[(wm * 64 + i * 16 + fr) * 32 + sz8];
#pragma unroll
        for (int j = 0; j < 4; ++j) {
            bf16x8 bF = *(const bf16x8*)&bT[(wn * 64 + j * 16 + fr) * 32 + sz8];
#pragma unroll
            for (int i = 0; i < 4; ++i)
                acc[i][j] = __builtin_amdgcn_mfma_f32_16x16x32_bf16(aF[i], bF, acc[i][j], 0, 0, 0);
        }
        __syncthreads();
    }

    int cbase = n0 + wn * 64 + fr;
    int rbase = m0 + wm * 64 + (lane >> 4) * 4;
#pragma unroll
    for (int i = 0; i < 4; ++i) {
#pragma unroll
        for (int r = 0; r < 4; ++r) {
            int gr = rbase + i * 16 + r;
            if (gr >= cnt) continue;
            int gp = base + gr;
            float pw = pair_prob[gp];
            float* orow = out + (size_t)pair_token[gp] * DMODEL;
#pragma unroll
            for (int j = 0; j < 4; ++j)
                atomicAdd(&orow[cbase + j * 16], pw * acc[i][j][r]);
        }
    }
}

// ---------------- launch ----------------
extern "C" void kernel_launch(void* const* d_in, const int* in_sizes, int n_in,
                              void* d_out, int out_size, void* d_ws, size_t ws_size,
                              hipStream_t stream)
{
    const float* x  = (const float*)d_in[0];
    const float* rw = (const float*)d_in[1];
    const float* w1 = (const float*)d_in[2];
    const float* w2 = (const float*)d_in[3];
    const float* w3 = (const float*)d_in[4];
    float* out = (float*)d_out;

    char* ws = (char*)d_ws;
    int*   pair_count = (int*)(ws + 0);
    int*   offsets    = (int*)(ws + 32);
    int*   cursor     = (int*)(ws + 64);
    float* blk_psum   = (float*)(ws + 256);
    int*   blk_t1     = (int*)(ws + 65792);
    int*   blk_pc     = (int*)(ws + 131328);
    int*   topk_idx   = (int*)(ws + 196864);
    float* topk_p     = (float*)(ws + 262400);
    int*   pair_token = (int*)(ws + 327936);
    float* pair_prob  = (float*)(ws + 393472);
    unsigned short* xb  = (unsigned short*)(ws + 459264);
    unsigned short* w1b = (unsigned short*)(ws + 17236480);
    unsigned short* w3b = (unsigned short*)(ws + 28443136);
    unsigned short* w2b = (unsigned short*)(ws + 39649792);
    unsigned short* hbuf= (unsigned short*)(ws + 51184128);

    hipMemsetAsync(d_out, 0, (size_t)out_size * sizeof(float), stream);

    cvt_bf16x4<<<(NEXP * HDIM * DMODEL / 4 + 255) / 256, 256, 0, stream>>>(w1, w1b, NEXP * HDIM * DMODEL / 4);
    cvt_bf16x4<<<(NEXP * HDIM * DMODEL / 4 + 255) / 256, 256, 0, stream>>>(w3, w3b, NEXP * HDIM * DMODEL / 4);
    cvt_w2_pad<<<(NEXP * DMODEL * (HPAD / 4) + 255) / 256, 256, 0, stream>>>(w2, w2b, NEXP * DMODEL * (HPAD / 4));

    moe_router <<<T_TOK / 4, 256, 0, stream>>>(x, rw, xb, blk_psum, blk_t1, blk_pc, topk_idx, topk_p);
    moe_scan   <<<1, 256, 0, stream>>>(blk_psum, blk_t1, blk_pc, pair_count, offsets, cursor,
                                       out + (size_t)T_TOK * DMODEL);
    moe_scatter<<<T_TOK / 256, 256, 0, stream>>>(topk_idx, topk_p, cursor, pair_token, pair_prob);

    moe_ffn1<<<dim3(6, 64, 8), 256, 0, stream>>>(xb, w1b, w3b, pair_count, offsets, pair_token, hbuf);
    moe_ffn2<<<dim3(8, 64, 8), 256, 0, stream>>>(hbuf, w2b, pair_count, offsets, pair_token, pair_prob, out);
}

// Round 4
// 333.844 us; speedup vs baseline: 7.6597x; 1.2577x over previous
//
#include <hip/hip_runtime.h>
#include <hip/hip_bf16.h>

#define T_TOK 8192
#define DMODEL 1024
#define HDIM 684
#define HPAD 704
#define NEXP 8

typedef short  bf16x8  __attribute__((ext_vector_type(8)));
typedef float  f32x4   __attribute__((ext_vector_type(4)));

__device__ inline unsigned short f2bu(float f) {
    __hip_bfloat16 h = __float2bfloat16(f);   // RNE
    return *reinterpret_cast<unsigned short*>(&h);
}

typedef const __attribute__((address_space(1))) unsigned int* gas_p;
typedef __attribute__((address_space(3))) unsigned int* las_p;
__device__ inline void ld_lds16(const unsigned short* g, unsigned short* l) {
    __builtin_amdgcn_global_load_lds((gas_p)g, (las_p)l, 16, 0, 0);
}

// ---------------- workspace layout (bytes) ----------------
// 0        pair_count[8]@0, offsets[8]@32, cursor[8]@64
// 256      blk_psum f32[2048*8]
// 65792    blk_t1   i32[2048*8]
// 131328   blk_pc   i32[2048*8]
// 196864   topk_idx i32[16384]
// 262400   topk_p   f32[16384]
// 327936   pair_token i32[16384]
// 393472   pair_prob  f32[16384]
// 459264   xb  bf16[8192*1024]
// 17236480 w1b bf16[8*684*1024]
// 28443136 w3b bf16[8*684*1024]
// 39649792 w2b bf16[8*1024*704]  (K padded+zeroed)
// 51184128 h   bf16[16384*704]   (cols 684..703 zeroed by ffn1)

// ---------------- conversions ----------------
__global__ __launch_bounds__(256) void cvt_bf16x4(
    const float* __restrict__ src, unsigned short* __restrict__ dst, int n4)
{
    int i = blockIdx.x * 256 + threadIdx.x;
    if (i >= n4) return;
    float4 v = ((const float4*)src)[i];
    ushort4 o = make_ushort4(f2bu(v.x), f2bu(v.y), f2bu(v.z), f2bu(v.w));
    ((ushort4*)dst)[i] = o;
}

__global__ __launch_bounds__(256) void cvt_w2_pad(
    const float* __restrict__ w2, unsigned short* __restrict__ w2b, int n)
{
    int i = blockIdx.x * 256 + threadIdx.x;
    if (i >= n) return;
    int row = i / 176;
    int col = (i - row * 176) * 4;
    ushort4 o = make_ushort4(0, 0, 0, 0);
    if (col < HDIM) {
        float4 v = *(const float4*)(w2 + (size_t)row * HDIM + col);
        o = make_ushort4(f2bu(v.x), f2bu(v.y), f2bu(v.z), f2bu(v.w));
    }
    *(ushort4*)(w2b + (size_t)row * HPAD + col) = o;
}

// ---------------- 1. router (+ fused x->bf16) ----------------
__global__ __launch_bounds__(256) void moe_router(
    const float* __restrict__ x, const float* __restrict__ rw,
    unsigned short* __restrict__ xb,
    float* __restrict__ blk_psum, int* __restrict__ blk_t1, int* __restrict__ blk_pc,
    int* __restrict__ topk_idx, float* __restrict__ topk_p)
{
    __shared__ float sp[4][NEXP];
    __shared__ int   si1[4], si2[4];

    int lane = threadIdx.x & 63;
    int w    = threadIdx.x >> 6;
    int t    = blockIdx.x * 4 + w;
    const float* xr = x + (size_t)t * DMODEL;
    unsigned short* xbr = xb + (size_t)t * DMODEL;

    float acc[NEXP];
#pragma unroll
    for (int e = 0; e < NEXP; ++e) acc[e] = 0.f;
#pragma unroll
    for (int j = 0; j < DMODEL / 64; ++j) {
        float xv = xr[j * 64 + lane];
        xbr[j * 64 + lane] = f2bu(xv);
#pragma unroll
        for (int e = 0; e < NEXP; ++e)
            acc[e] += xv * rw[e * DMODEL + j * 64 + lane];
    }
#pragma unroll
    for (int off = 32; off > 0; off >>= 1) {
#pragma unroll
        for (int e = 0; e < NEXP; ++e)
            acc[e] += __shfl_xor(acc[e], off, 64);
    }
    if (lane == 0) {
        float m = acc[0];
#pragma unroll
        for (int e = 1; e < NEXP; ++e) m = fmaxf(m, acc[e]);
        float p[NEXP]; float s = 0.f;
#pragma unroll
        for (int e = 0; e < NEXP; ++e) { p[e] = expf(acc[e] - m); s += p[e]; }
        float inv = 1.f / s;
#pragma unroll
        for (int e = 0; e < NEXP; ++e) p[e] *= inv;
        int i1 = 0;
#pragma unroll
        for (int e = 1; e < NEXP; ++e) if (p[e] > p[i1]) i1 = e;
        int i2 = (i1 == 0) ? 1 : 0;
#pragma unroll
        for (int e = 0; e < NEXP; ++e) if (e != i1 && p[e] > p[i2]) i2 = e;

        topk_idx[t * 2 + 0] = i1;  topk_idx[t * 2 + 1] = i2;
        topk_p[t * 2 + 0] = p[i1]; topk_p[t * 2 + 1] = p[i2];
#pragma unroll
        for (int e = 0; e < NEXP; ++e) sp[w][e] = p[e];
        si1[w] = i1; si2[w] = i2;
    }
    __syncthreads();
    if (threadIdx.x < NEXP) {
        int e = threadIdx.x;
        float ps = sp[0][e] + sp[1][e] + sp[2][e] + sp[3][e];
        int t1 = (si1[0] == e) + (si1[1] == e) + (si1[2] == e) + (si1[3] == e);
        int pc = t1 + (si2[0] == e) + (si2[1] == e) + (si2[2] == e) + (si2[3] == e);
        blk_psum[blockIdx.x * NEXP + e] = ps;
        blk_t1[blockIdx.x * NEXP + e]  = t1;
        blk_pc[blockIdx.x * NEXP + e]  = pc;
    }
}

// ---------------- 2. scan ----------------
__global__ __launch_bounds__(256) void moe_scan(
    const float* __restrict__ blk_psum, const int* __restrict__ blk_t1,
    const int* __restrict__ blk_pc,
    int* pair_count, int* offsets, int* cursor, float* aux_out)
{
    __shared__ float rp[256][NEXP];
    __shared__ int   rt[256][NEXP], rc[256][NEXP];
    __shared__ float tp[NEXP];
    __shared__ int   tt1[NEXP], tpc[NEXP];

    int tid = threadIdx.x;
    float lp[NEXP]; int lt[NEXP], lc[NEXP];
#pragma unroll
    for (int e = 0; e < NEXP; ++e) { lp[e] = 0.f; lt[e] = 0; lc[e] = 0; }
    for (int b = tid; b < 2048; b += 256)
#pragma unroll
        for (int e = 0; e < NEXP; ++e) {
            lp[e] += blk_psum[b * NEXP + e];
            lt[e] += blk_t1[b * NEXP + e];
            lc[e] += blk_pc[b * NEXP + e];
        }
#pragma unroll
    for (int e = 0; e < NEXP; ++e) { rp[tid][e] = lp[e]; rt[tid][e] = lt[e]; rc[tid][e] = lc[e]; }
    __syncthreads();
    if (tid < NEXP) {
        float s = 0.f; int t1 = 0, pc = 0;
        for (int i = 0; i < 256; ++i) { s += rp[i][tid]; t1 += rt[i][tid]; pc += rc[i][tid]; }
        tp[tid] = s; tt1[tid] = t1; tpc[tid] = pc;
        pair_count[tid] = pc;
    }
    __syncthreads();
    if (tid == 0) {
        int run = 0;
        for (int e = 0; e < NEXP; ++e) { offsets[e] = run; cursor[e] = run; run += tpc[e]; }
        float s = 0.f;
        for (int e = 0; e < NEXP; ++e)
            s += ((float)tt1[e] / (float)T_TOK) * (tp[e] / (float)T_TOK);
        aux_out[0] = 0.01f * s * (float)NEXP;
    }
}

// ---------------- 3. scatter ----------------
__global__ __launch_bounds__(256) void moe_scatter(
    const int* __restrict__ topk_idx, const float* __restrict__ topk_p,
    int* cursor, int* __restrict__ pair_token, float* __restrict__ pair_prob)
{
    __shared__ int lcnt[NEXP], gbase[NEXP];
    int tid = threadIdx.x;
    if (tid < NEXP) lcnt[tid] = 0;
    __syncthreads();
    int t = blockIdx.x * 256 + tid;
    int e0 = topk_idx[t * 2 + 0], e1 = topk_idx[t * 2 + 1];
    int p0 = atomicAdd(&lcnt[e0], 1);
    int p1 = atomicAdd(&lcnt[e1], 1);
    __syncthreads();
    if (tid < NEXP) gbase[tid] = atomicAdd(&cursor[tid], lcnt[tid]);
    __syncthreads();
    int q0 = gbase[e0] + p0, q1 = gbase[e1] + p1;
    pair_token[q0] = t; pair_prob[q0] = topk_p[t * 2 + 0];
    pair_token[q1] = t; pair_prob[q1] = topk_p[t * 2 + 1];
}

// LDS tile: 128 rows x 32 k (bf16), flat 4096 ushorts, 16B granules.
// physical granule(row, kseg) = row*4 + (kseg ^ ((row>>1)&3))
// -> ds_read_b128 frag reads: 16 lanes per kseg-group hit each 4-bank start
//    group exactly twice => 2-way (free, m136). Staging writes lane-contiguous.
// Staging lane L of chunk c: row = 16c + (L>>2), logical kseg = (L&3)^((L>>3)&3).

// ---------------- 4. MFMA GEMM1: h = silu(Xg w1^T) * (Xg w3^T) ----------------
// grid (6, 64, 8); 512 thr = 8 waves; tile 128x128, wave-tile 32x64, BK=32
__global__ __launch_bounds__(512) void moe_ffn1(
    const unsigned short* __restrict__ xb, const unsigned short* __restrict__ w1b,
    const unsigned short* __restrict__ w3b,
    const int* __restrict__ pair_count, const int* __restrict__ offsets,
    const int* __restrict__ pair_token,
    unsigned short* __restrict__ h)
{
    int e   = blockIdx.z;
    int cnt = pair_count[e];
    int m0  = blockIdx.y * 128;
    if (m0 >= cnt) return;
    int base = offsets[e];
    int n0   = blockIdx.x * 128;

    __shared__ unsigned short aT[4096];
    __shared__ unsigned short b1T[4096];
    __shared__ unsigned short b3T[4096];

    int tid  = threadIdx.x;
    int lane = tid & 63, wave = tid >> 6;     // 8 waves
    int wm = wave >> 1, wn = wave & 1;        // wave-tile: rows wm*32, cols wn*64

    // staging: wave stages 16-row chunk `wave` of A, B1, B3 (1 granule/lane each)
    int srow = lane >> 2;
    int ksg  = (lane & 3) ^ ((lane >> 3) & 3);
    int arow = m0 + wave * 16 + srow; if (arow >= cnt) arow = cnt - 1;
    const unsigned short* ap  = xb + (size_t)pair_token[base + arow] * DMODEL + ksg * 8;
    int brow = n0 + wave * 16 + srow; if (brow > HDIM - 1) brow = HDIM - 1;
    const unsigned short* b1p = w1b + ((size_t)e * HDIM + brow) * DMODEL + ksg * 8;
    const unsigned short* b3p = w3b + ((size_t)e * HDIM + brow) * DMODEL + ksg * 8;
    unsigned short* lA  = &aT[wave * 512];
    unsigned short* lB1 = &b1T[wave * 512];
    unsigned short* lB3 = &b3T[wave * 512];

    f32x4 acc1[2][4], acc3[2][4];             // 64 AGPR total
#pragma unroll
    for (int i = 0; i < 2; ++i)
#pragma unroll
        for (int j = 0; j < 4; ++j) { acc1[i][j] = (f32x4)(0.f); acc3[i][j] = (f32x4)(0.f); }

    int fr  = lane & 15;
    int sz8 = ((lane >> 4) ^ ((fr >> 1) & 3)) * 8;

    for (int k0 = 0; k0 < DMODEL; k0 += 32) {
        ld_lds16(ap + k0, lA);
        ld_lds16(b1p + k0, lB1);
        ld_lds16(b3p + k0, lB3);
        __syncthreads();

        bf16x8 aF[2];
#pragma unroll
        for (int i = 0; i < 2; ++i)
            aF[i] = *(const bf16x8*)&aT[(wm * 32 + i * 16 + fr) * 32 + sz8];
#pragma unroll
        for (int j = 0; j < 4; ++j) {
            int row = (wn * 64 + j * 16 + fr) * 32 + sz8;
            bf16x8 b1F = *(const bf16x8*)&b1T[row];
            bf16x8 b3F = *(const bf16x8*)&b3T[row];
#pragma unroll
            for (int i = 0; i < 2; ++i) {
                acc1[i][j] = __builtin_amdgcn_mfma_f32_16x16x32_bf16(aF[i], b1F, acc1[i][j], 0, 0, 0);
                acc3[i][j] = __builtin_amdgcn_mfma_f32_16x16x32_bf16(aF[i], b3F, acc3[i][j], 0, 0, 0);
            }
        }
        __syncthreads();
    }

    int cbase = n0 + wn * 64 + fr;
    int rbase = m0 + wm * 32 + (lane >> 4) * 4;
#pragma unroll
    for (int i = 0; i < 2; ++i) {
#pragma unroll
        for (int r = 0; r < 4; ++r) {
            int gr = rbase + i * 16 + r;
            if (gr >= cnt) continue;
            unsigned short* hrow = h + (size_t)(base + gr) * HPAD;
#pragma unroll
            for (int j = 0; j < 4; ++j) {
                int col = cbase + j * 16;
                if (col >= HPAD) continue;
                float v1 = acc1[i][j][r];
                float hv = (col < HDIM) ? (v1 / (1.f + expf(-v1))) * acc3[i][j][r] : 0.f;
                hrow[col] = f2bu(hv);
            }
        }
    }
}

// ---------------- 5. MFMA GEMM2: out[tok] += p * (h w2^T) ----------------
// grid (8, 64, 8); 512 thr = 8 waves; tile 128x128, wave-tile 32x64, K=704
__global__ __launch_bounds__(512) void moe_ffn2(
    const unsigned short* __restrict__ h, const unsigned short* __restrict__ w2b,
    const int* __restrict__ pair_count, const int* __restrict__ offsets,
    const int* __restrict__ pair_token, const float* __restrict__ pair_prob,
    float* __restrict__ out)
{
    int e   = blockIdx.z;
    int cnt = pair_count[e];
    int m0  = blockIdx.y * 128;
    if (m0 >= cnt) return;
    int base = offsets[e];
    int n0   = blockIdx.x * 128;

    __shared__ unsigned short aT[4096];
    __shared__ unsigned short bT[4096];

    int tid  = threadIdx.x;
    int lane = tid & 63, wave = tid >> 6;
    int wm = wave >> 1, wn = wave & 1;

    int srow = lane >> 2;
    int ksg  = (lane & 3) ^ ((lane >> 3) & 3);
    int arow = m0 + wave * 16 + srow; if (arow >= cnt) arow = cnt - 1;
    const unsigned short* ap = h + (size_t)(base + arow) * HPAD + ksg * 8;
    const unsigned short* bp = w2b + ((size_t)e * DMODEL + n0 + wave * 16 + srow) * HPAD + ksg * 8;
    unsigned short* lA = &aT[wave * 512];
    unsigned short* lB = &bT[wave * 512];

    f32x4 acc[2][4];                          // 32 AGPR
#pragma unroll
    for (int i = 0; i < 2; ++i)
#pragma unroll
        for (int j = 0; j < 4; ++j) acc[i][j] = (f32x4)(0.f);

    int fr  = lane & 15;
    int sz8 = ((lane >> 4) ^ ((fr >> 1) & 3)) * 8;

    for (int k0 = 0; k0 < HPAD; k0 += 32) {
        ld_lds16(ap + k0, lA);
        ld_lds16(bp + k0, lB);
        __syncthreads();

        bf16x8 aF[2];
#pragma unroll
        for (int i = 0; i < 2; ++i)
            aF[i] = *(const bf16x8*)&aT[(wm * 32 + i * 16 + fr) * 32 + sz8];
#pragma unroll
        for (int j = 0; j < 4; ++j) {
            bf16x8 bF = *(const bf16x8*)&bT[(wn * 64 + j * 16 + fr) * 32 + sz8];
#pragma unroll
            for (int i = 0; i < 2; ++i)
                acc[i][j] = __builtin_amdgcn_mfma_f32_16x16x32_bf16(aF[i], bF, acc[i][j], 0, 0, 0);
        }
        __syncthreads();
    }

    int cbase = n0 + wn * 64 + fr;
    int rbase = m0 + wm * 32 + (lane >> 4) * 4;
#pragma unroll
    for (int i = 0; i < 2; ++i) {
#pragma unroll
        for (int r = 0; r < 4; ++r) {
            int gr = rbase + i * 16 + r;
            if (gr >= cnt) continue;
            int gp = base + gr;
            float pw = pair_prob[gp];
            float* orow = out + (size_t)pair_token[gp] * DMODEL;
#pragma unroll
            for (int j = 0; j < 4; ++j)
                atomicAdd(&orow[cbase + j * 16], pw * acc[i][j][r]);
        }
    }
}

// ---------------- launch ----------------
extern "C" void kernel_launch(void* const* d_in, const int* in_sizes, int n_in,
                              void* d_out, int out_size, void* d_ws, size_t ws_size,
                              hipStream_t stream)
{
    const float* x  = (const float*)d_in[0];
    const float* rw = (const float*)d_in[1];
    const float* w1 = (const float*)d_in[2];
    const float* w2 = (const float*)d_in[3];
    const float* w3 = (const float*)d_in[4];
    float* out = (float*)d_out;

    char* ws = (char*)d_ws;
    int*   pair_count = (int*)(ws + 0);
    int*   offsets    = (int*)(ws + 32);
    int*   cursor     = (int*)(ws + 64);
    float* blk_psum   = (float*)(ws + 256);
    int*   blk_t1     = (int*)(ws + 65792);
    int*   blk_pc     = (int*)(ws + 131328);
    int*   topk_idx   = (int*)(ws + 196864);
    float* topk_p     = (float*)(ws + 262400);
    int*   pair_token = (int*)(ws + 327936);
    float* pair_prob  = (float*)(ws + 393472);
    unsigned short* xb  = (unsigned short*)(ws + 459264);
    unsigned short* w1b = (unsigned short*)(ws + 17236480);
    unsigned short* w3b = (unsigned short*)(ws + 28443136);
    unsigned short* w2b = (unsigned short*)(ws + 39649792);
    unsigned short* hbuf= (unsigned short*)(ws + 51184128);

    hipMemsetAsync(d_out, 0, (size_t)out_size * sizeof(float), stream);

    cvt_bf16x4<<<(NEXP * HDIM * DMODEL / 4 + 255) / 256, 256, 0, stream>>>(w1, w1b, NEXP * HDIM * DMODEL / 4);
    cvt_bf16x4<<<(NEXP * HDIM * DMODEL / 4 + 255) / 256, 256, 0, stream>>>(w3, w3b, NEXP * HDIM * DMODEL / 4);
    cvt_w2_pad<<<(NEXP * DMODEL * (HPAD / 4) + 255) / 256, 256, 0, stream>>>(w2, w2b, NEXP * DMODEL * (HPAD / 4));

    moe_router <<<T_TOK / 4, 256, 0, stream>>>(x, rw, xb, blk_psum, blk_t1, blk_pc, topk_idx, topk_p);
    moe_scan   <<<1, 256, 0, stream>>>(blk_psum, blk_t1, blk_pc, pair_count, offsets, cursor,
                                       out + (size_t)T_TOK * DMODEL);
    moe_scatter<<<T_TOK / 256, 256, 0, stream>>>(topk_idx, topk_p, cursor, pair_token, pair_prob);

    moe_ffn1<<<dim3(6, 64, 8), 512, 0, stream>>>(xb, w1b, w3b, pair_count, offsets, pair_token, hbuf);
    moe_ffn2<<<dim3(8, 64, 8), 512, 0, stream>>>(hbuf, w2b, pair_count, offsets, pair_token, pair_prob, out);
}

// Round 5
// 326.414 us; speedup vs baseline: 7.8341x; 1.0228x over previous
//
#include <hip/hip_runtime.h>
#include <hip/hip_bf16.h>

#define T_TOK 8192
#define DMODEL 1024
#define HDIM 684
#define HPAD 704
#define NEXP 8

typedef short  bf16x8  __attribute__((ext_vector_type(8)));
typedef float  f32x4   __attribute__((ext_vector_type(4)));

__device__ inline unsigned short f2bu(float f) {
    __hip_bfloat16 h = __float2bfloat16(f);   // RNE
    return *reinterpret_cast<unsigned short*>(&h);
}

typedef const __attribute__((address_space(1))) unsigned int* gas_p;
typedef __attribute__((address_space(3))) unsigned int* las_p;
__device__ inline void ld_lds16(const unsigned short* g, unsigned short* l) {
    __builtin_amdgcn_global_load_lds((gas_p)g, (las_p)l, 16, 0, 0);
}

// ---------------- workspace layout (bytes) ----------------
// 0        pair_count[8]@0, offsets[8]@32, cursor[8]@64
// 256      blk_psum f32[2048*8]
// 65792    blk_t1   i32[2048*8]
// 131328   blk_pc   i32[2048*8]
// 196864   topk_idx i32[16384]
// 262400   topk_p   f32[16384]
// 327936   pair_token i32[16384]
// 393472   pair_prob  f32[16384]
// 459264   xb  bf16[8192*1024]
// 17236480 w1b bf16[8*684*1024]
// 28443136 w3b bf16[8*684*1024]
// 39649792 w2b bf16[8*1024*704]  (K padded+zeroed)
// 51184128 h   bf16[16384*704]   (cols 684..703 zeroed by ffn1)

// ---------------- conversions ----------------
// w1 and w3 in one launch: flat over 2*n4 granules
__global__ __launch_bounds__(256) void cvt_w13(
    const float* __restrict__ w1, const float* __restrict__ w3,
    unsigned short* __restrict__ w1b, unsigned short* __restrict__ w3b, int n4)
{
    int i = blockIdx.x * 256 + threadIdx.x;
    const float* src; unsigned short* dst; int j;
    if (i < n4) { src = w1; dst = w1b; j = i; }
    else if (i < 2 * n4) { src = w3; dst = w3b; j = i - n4; }
    else return;
    float4 v = ((const float4*)src)[j];
    ushort4 o = make_ushort4(f2bu(v.x), f2bu(v.y), f2bu(v.z), f2bu(v.w));
    ((ushort4*)dst)[j] = o;
}

__global__ __launch_bounds__(256) void cvt_w2_pad(
    const float* __restrict__ w2, unsigned short* __restrict__ w2b, int n)
{
    int i = blockIdx.x * 256 + threadIdx.x;
    if (i >= n) return;
    int row = i / 176;
    int col = (i - row * 176) * 4;
    ushort4 o = make_ushort4(0, 0, 0, 0);
    if (col < HDIM) {
        float4 v = *(const float4*)(w2 + (size_t)row * HDIM + col);
        o = make_ushort4(f2bu(v.x), f2bu(v.y), f2bu(v.z), f2bu(v.w));
    }
    *(ushort4*)(w2b + (size_t)row * HPAD + col) = o;
}

// ---------------- 1. router (+ fused x->bf16) ----------------
__global__ __launch_bounds__(256) void moe_router(
    const float* __restrict__ x, const float* __restrict__ rw,
    unsigned short* __restrict__ xb,
    float* __restrict__ blk_psum, int* __restrict__ blk_t1, int* __restrict__ blk_pc,
    int* __restrict__ topk_idx, float* __restrict__ topk_p)
{
    __shared__ float sp[4][NEXP];
    __shared__ int   si1[4], si2[4];

    int lane = threadIdx.x & 63;
    int w    = threadIdx.x >> 6;
    int t    = blockIdx.x * 4 + w;
    const float* xr = x + (size_t)t * DMODEL;
    unsigned short* xbr = xb + (size_t)t * DMODEL;

    float acc[NEXP];
#pragma unroll
    for (int e = 0; e < NEXP; ++e) acc[e] = 0.f;
#pragma unroll
    for (int j = 0; j < DMODEL / 64; ++j) {
        float xv = xr[j * 64 + lane];
        xbr[j * 64 + lane] = f2bu(xv);
#pragma unroll
        for (int e = 0; e < NEXP; ++e)
            acc[e] += xv * rw[e * DMODEL + j * 64 + lane];
    }
#pragma unroll
    for (int off = 32; off > 0; off >>= 1) {
#pragma unroll
        for (int e = 0; e < NEXP; ++e)
            acc[e] += __shfl_xor(acc[e], off, 64);
    }
    if (lane == 0) {
        float m = acc[0];
#pragma unroll
        for (int e = 1; e < NEXP; ++e) m = fmaxf(m, acc[e]);
        float p[NEXP]; float s = 0.f;
#pragma unroll
        for (int e = 0; e < NEXP; ++e) { p[e] = expf(acc[e] - m); s += p[e]; }
        float inv = 1.f / s;
#pragma unroll
        for (int e = 0; e < NEXP; ++e) p[e] *= inv;
        int i1 = 0;
#pragma unroll
        for (int e = 1; e < NEXP; ++e) if (p[e] > p[i1]) i1 = e;
        int i2 = (i1 == 0) ? 1 : 0;
#pragma unroll
        for (int e = 0; e < NEXP; ++e) if (e != i1 && p[e] > p[i2]) i2 = e;

        topk_idx[t * 2 + 0] = i1;  topk_idx[t * 2 + 1] = i2;
        topk_p[t * 2 + 0] = p[i1]; topk_p[t * 2 + 1] = p[i2];
#pragma unroll
        for (int e = 0; e < NEXP; ++e) sp[w][e] = p[e];
        si1[w] = i1; si2[w] = i2;
    }
    __syncthreads();
    if (threadIdx.x < NEXP) {
        int e = threadIdx.x;
        float ps = sp[0][e] + sp[1][e] + sp[2][e] + sp[3][e];
        int t1 = (si1[0] == e) + (si1[1] == e) + (si1[2] == e) + (si1[3] == e);
        int pc = t1 + (si2[0] == e) + (si2[1] == e) + (si2[2] == e) + (si2[3] == e);
        blk_psum[blockIdx.x * NEXP + e] = ps;
        blk_t1[blockIdx.x * NEXP + e]  = t1;
        blk_pc[blockIdx.x * NEXP + e]  = pc;
    }
}

// ---------------- 2. scan ----------------
__global__ __launch_bounds__(256) void moe_scan(
    const float* __restrict__ blk_psum, const int* __restrict__ blk_t1,
    const int* __restrict__ blk_pc,
    int* pair_count, int* offsets, int* cursor, float* aux_out)
{
    __shared__ float rp[256][NEXP];
    __shared__ int   rt[256][NEXP], rc[256][NEXP];
    __shared__ float tp[NEXP];
    __shared__ int   tt1[NEXP], tpc[NEXP];

    int tid = threadIdx.x;
    float lp[NEXP]; int lt[NEXP], lc[NEXP];
#pragma unroll
    for (int e = 0; e < NEXP; ++e) { lp[e] = 0.f; lt[e] = 0; lc[e] = 0; }
    for (int b = tid; b < 2048; b += 256)
#pragma unroll
        for (int e = 0; e < NEXP; ++e) {
            lp[e] += blk_psum[b * NEXP + e];
            lt[e] += blk_t1[b * NEXP + e];
            lc[e] += blk_pc[b * NEXP + e];
        }
#pragma unroll
    for (int e = 0; e < NEXP; ++e) { rp[tid][e] = lp[e]; rt[tid][e] = lt[e]; rc[tid][e] = lc[e]; }
    __syncthreads();
    if (tid < NEXP) {
        float s = 0.f; int t1 = 0, pc = 0;
        for (int i = 0; i < 256; ++i) { s += rp[i][tid]; t1 += rt[i][tid]; pc += rc[i][tid]; }
        tp[tid] = s; tt1[tid] = t1; tpc[tid] = pc;
        pair_count[tid] = pc;
    }
    __syncthreads();
    if (tid == 0) {
        int run = 0;
        for (int e = 0; e < NEXP; ++e) { offsets[e] = run; cursor[e] = run; run += tpc[e]; }
        float s = 0.f;
        for (int e = 0; e < NEXP; ++e)
            s += ((float)tt1[e] / (float)T_TOK) * (tp[e] / (float)T_TOK);
        aux_out[0] = 0.01f * s * (float)NEXP;
    }
}

// ---------------- 3. scatter ----------------
__global__ __launch_bounds__(256) void moe_scatter(
    const int* __restrict__ topk_idx, const float* __restrict__ topk_p,
    int* cursor, int* __restrict__ pair_token, float* __restrict__ pair_prob)
{
    __shared__ int lcnt[NEXP], gbase[NEXP];
    int tid = threadIdx.x;
    if (tid < NEXP) lcnt[tid] = 0;
    __syncthreads();
    int t = blockIdx.x * 256 + tid;
    int e0 = topk_idx[t * 2 + 0], e1 = topk_idx[t * 2 + 1];
    int p0 = atomicAdd(&lcnt[e0], 1);
    int p1 = atomicAdd(&lcnt[e1], 1);
    __syncthreads();
    if (tid < NEXP) gbase[tid] = atomicAdd(&cursor[tid], lcnt[tid]);
    __syncthreads();
    int q0 = gbase[e0] + p0, q1 = gbase[e1] + p1;
    pair_token[q0] = t; pair_prob[q0] = topk_p[t * 2 + 0];
    pair_token[q1] = t; pair_prob[q1] = topk_p[t * 2 + 1];
}

// LDS tile: 128 rows x 32 k (bf16), flat 4096 ushorts, 16B granules,
// physical granule(row,kseg) = row*4 + (kseg ^ ((row>>1)&3))  -> conflict-free
// (verified R4: SQ_LDS_BANK_CONFLICT == 0). Double-buffered (ping-pong):
//   prologue: glds tile0 -> buf0
//   iter k:   barrier; glds tile(k+1) -> buf^1; ds_read+MFMA from buf
// Single barrier per iter; the vmcnt(0) drain at the barrier waits on loads
// that had a full compute phase in flight.

// ---------------- 4. MFMA GEMM1: h = silu(Xg w1^T) * (Xg w3^T) ----------------
// grid (6, 64, 8); 512 thr = 8 waves; tile 128x128, wave-tile 32x64, BK=32
__global__ __launch_bounds__(512) void moe_ffn1(
    const unsigned short* __restrict__ xb, const unsigned short* __restrict__ w1b,
    const unsigned short* __restrict__ w3b,
    const int* __restrict__ pair_count, const int* __restrict__ offsets,
    const int* __restrict__ pair_token,
    unsigned short* __restrict__ h)
{
    int e   = blockIdx.z;
    int cnt = pair_count[e];
    int m0  = blockIdx.y * 128;
    if (m0 >= cnt) return;
    int base = offsets[e];
    int n0   = blockIdx.x * 128;

    __shared__ unsigned short aT[2][4096];
    __shared__ unsigned short b1T[2][4096];
    __shared__ unsigned short b3T[2][4096];

    int tid  = threadIdx.x;
    int lane = tid & 63, wave = tid >> 6;
    int wm = wave >> 1, wn = wave & 1;

    int srow = lane >> 2;
    int ksg  = (lane & 3) ^ ((lane >> 3) & 3);
    int arow = m0 + wave * 16 + srow; if (arow >= cnt) arow = cnt - 1;
    const unsigned short* ap  = xb + (size_t)pair_token[base + arow] * DMODEL + ksg * 8;
    int brow = n0 + wave * 16 + srow; if (brow > HDIM - 1) brow = HDIM - 1;
    const unsigned short* b1p = w1b + ((size_t)e * HDIM + brow) * DMODEL + ksg * 8;
    const unsigned short* b3p = w3b + ((size_t)e * HDIM + brow) * DMODEL + ksg * 8;
    unsigned short* lA[2]  = { &aT[0][wave * 512],  &aT[1][wave * 512]  };
    unsigned short* lB1[2] = { &b1T[0][wave * 512], &b1T[1][wave * 512] };
    unsigned short* lB3[2] = { &b3T[0][wave * 512], &b3T[1][wave * 512] };

    f32x4 acc1[2][4], acc3[2][4];
#pragma unroll
    for (int i = 0; i < 2; ++i)
#pragma unroll
        for (int j = 0; j < 4; ++j) { acc1[i][j] = (f32x4)(0.f); acc3[i][j] = (f32x4)(0.f); }

    int fr  = lane & 15;
    int sz8 = ((lane >> 4) ^ ((fr >> 1) & 3)) * 8;

    // prologue
    ld_lds16(ap, lA[0]);
    ld_lds16(b1p, lB1[0]);
    ld_lds16(b3p, lB3[0]);

    const int NIT = DMODEL / 32;   // 32
    for (int it = 0; it < NIT; ++it) {
        int buf = it & 1;
        __syncthreads();                       // drains glds of tile `it`
        if (it + 1 < NIT) {
            int nk = (it + 1) * 32;
            ld_lds16(ap + nk,  lA[buf ^ 1]);
            ld_lds16(b1p + nk, lB1[buf ^ 1]);
            ld_lds16(b3p + nk, lB3[buf ^ 1]);
        }
        const unsigned short* cA  = aT[buf];
        const unsigned short* cB1 = b1T[buf];
        const unsigned short* cB3 = b3T[buf];

        bf16x8 aF[2];
#pragma unroll
        for (int i = 0; i < 2; ++i)
            aF[i] = *(const bf16x8*)&cA[(wm * 32 + i * 16 + fr) * 32 + sz8];
#pragma unroll
        for (int j = 0; j < 4; ++j) {
            int row = (wn * 64 + j * 16 + fr) * 32 + sz8;
            bf16x8 b1F = *(const bf16x8*)&cB1[row];
            bf16x8 b3F = *(const bf16x8*)&cB3[row];
#pragma unroll
            for (int i = 0; i < 2; ++i) {
                acc1[i][j] = __builtin_amdgcn_mfma_f32_16x16x32_bf16(aF[i], b1F, acc1[i][j], 0, 0, 0);
                acc3[i][j] = __builtin_amdgcn_mfma_f32_16x16x32_bf16(aF[i], b3F, acc3[i][j], 0, 0, 0);
            }
        }
    }

    int cbase = n0 + wn * 64 + fr;
    int rbase = m0 + wm * 32 + (lane >> 4) * 4;
#pragma unroll
    for (int i = 0; i < 2; ++i) {
#pragma unroll
        for (int r = 0; r < 4; ++r) {
            int gr = rbase + i * 16 + r;
            if (gr >= cnt) continue;
            unsigned short* hrow = h + (size_t)(base + gr) * HPAD;
#pragma unroll
            for (int j = 0; j < 4; ++j) {
                int col = cbase + j * 16;
                if (col >= HPAD) continue;
                float v1 = acc1[i][j][r];
                float hv = (col < HDIM) ? (v1 / (1.f + expf(-v1))) * acc3[i][j][r] : 0.f;
                hrow[col] = f2bu(hv);
            }
        }
    }
}

// ---------------- 5. MFMA GEMM2: out[tok] += p * (h w2^T) ----------------
// grid (8, 64, 8); 512 thr = 8 waves; tile 128x128, wave-tile 32x64, K=704
__global__ __launch_bounds__(512) void moe_ffn2(
    const unsigned short* __restrict__ h, const unsigned short* __restrict__ w2b,
    const int* __restrict__ pair_count, const int* __restrict__ offsets,
    const int* __restrict__ pair_token, const float* __restrict__ pair_prob,
    float* __restrict__ out)
{
    int e   = blockIdx.z;
    int cnt = pair_count[e];
    int m0  = blockIdx.y * 128;
    if (m0 >= cnt) return;
    int base = offsets[e];
    int n0   = blockIdx.x * 128;

    __shared__ unsigned short aT[2][4096];
    __shared__ unsigned short bT[2][4096];

    int tid  = threadIdx.x;
    int lane = tid & 63, wave = tid >> 6;
    int wm = wave >> 1, wn = wave & 1;

    int srow = lane >> 2;
    int ksg  = (lane & 3) ^ ((lane >> 3) & 3);
    int arow = m0 + wave * 16 + srow; if (arow >= cnt) arow = cnt - 1;
    const unsigned short* ap = h + (size_t)(base + arow) * HPAD + ksg * 8;
    const unsigned short* bp = w2b + ((size_t)e * DMODEL + n0 + wave * 16 + srow) * HPAD + ksg * 8;
    unsigned short* lA[2] = { &aT[0][wave * 512], &aT[1][wave * 512] };
    unsigned short* lB[2] = { &bT[0][wave * 512], &bT[1][wave * 512] };

    f32x4 acc[2][4];
#pragma unroll
    for (int i = 0; i < 2; ++i)
#pragma unroll
        for (int j = 0; j < 4; ++j) acc[i][j] = (f32x4)(0.f);

    int fr  = lane & 15;
    int sz8 = ((lane >> 4) ^ ((fr >> 1) & 3)) * 8;

    ld_lds16(ap, lA[0]);
    ld_lds16(bp, lB[0]);

    const int NIT = HPAD / 32;   // 22
    for (int it = 0; it < NIT; ++it) {
        int buf = it & 1;
        __syncthreads();
        if (it + 1 < NIT) {
            int nk = (it + 1) * 32;
            ld_lds16(ap + nk, lA[buf ^ 1]);
            ld_lds16(bp + nk, lB[buf ^ 1]);
        }
        const unsigned short* cA = aT[buf];
        const unsigned short* cB = bT[buf];

        bf16x8 aF[2];
#pragma unroll
        for (int i = 0; i < 2; ++i)
            aF[i] = *(const bf16x8*)&cA[(wm * 32 + i * 16 + fr) * 32 + sz8];
#pragma unroll
        for (int j = 0; j < 4; ++j) {
            bf16x8 bF = *(const bf16x8*)&cB[(wn * 64 + j * 16 + fr) * 32 + sz8];
#pragma unroll
            for (int i = 0; i < 2; ++i)
                acc[i][j] = __builtin_amdgcn_mfma_f32_16x16x32_bf16(aF[i], bF, acc[i][j], 0, 0, 0);
        }
    }

    int cbase = n0 + wn * 64 + fr;
    int rbase = m0 + wm * 32 + (lane >> 4) * 4;
#pragma unroll
    for (int i = 0; i < 2; ++i) {
#pragma unroll
        for (int r = 0; r < 4; ++r) {
            int gr = rbase + i * 16 + r;
            if (gr >= cnt) continue;
            int gp = base + gr;
            float pw = pair_prob[gp];
            float* orow = out + (size_t)pair_token[gp] * DMODEL;
#pragma unroll
            for (int j = 0; j < 4; ++j)
                atomicAdd(&orow[cbase + j * 16], pw * acc[i][j][r]);
        }
    }
}

// ---------------- launch ----------------
extern "C" void kernel_launch(void* const* d_in, const int* in_sizes, int n_in,
                              void* d_out, int out_size, void* d_ws, size_t ws_size,
                              hipStream_t stream)
{
    const float* x  = (const float*)d_in[0];
    const float* rw = (const float*)d_in[1];
    const float* w1 = (const float*)d_in[2];
    const float* w2 = (const float*)d_in[3];
    const float* w3 = (const float*)d_in[4];
    float* out = (float*)d_out;

    char* ws = (char*)d_ws;
    int*   pair_count = (int*)(ws + 0);
    int*   offsets    = (int*)(ws + 32);
    int*   cursor     = (int*)(ws + 64);
    float* blk_psum   = (float*)(ws + 256);
    int*   blk_t1     = (int*)(ws + 65792);
    int*   blk_pc     = (int*)(ws + 131328);
    int*   topk_idx   = (int*)(ws + 196864);
    float* topk_p     = (float*)(ws + 262400);
    int*   pair_token = (int*)(ws + 327936);
    float* pair_prob  = (float*)(ws + 393472);
    unsigned short* xb  = (unsigned short*)(ws + 459264);
    unsigned short* w1b = (unsigned short*)(ws + 17236480);
    unsigned short* w3b = (unsigned short*)(ws + 28443136);
    unsigned short* w2b = (unsigned short*)(ws + 39649792);
    unsigned short* hbuf= (unsigned short*)(ws + 51184128);

    hipMemsetAsync(d_out, 0, (size_t)out_size * sizeof(float), stream);

    int n4 = NEXP * HDIM * DMODEL / 4;
    cvt_w13<<<(2 * n4 + 255) / 256, 256, 0, stream>>>(w1, w3, w1b, w3b, n4);
    cvt_w2_pad<<<(NEXP * DMODEL * (HPAD / 4) + 255) / 256, 256, 0, stream>>>(w2, w2b, NEXP * DMODEL * (HPAD / 4));

    moe_router <<<T_TOK / 4, 256, 0, stream>>>(x, rw, xb, blk_psum, blk_t1, blk_pc, topk_idx, topk_p);
    moe_scan   <<<1, 256, 0, stream>>>(blk_psum, blk_t1, blk_pc, pair_count, offsets, cursor,
                                       out + (size_t)T_TOK * DMODEL);
    moe_scatter<<<T_TOK / 256, 256, 0, stream>>>(topk_idx, topk_p, cursor, pair_token, pair_prob);

    moe_ffn1<<<dim3(6, 64, 8), 512, 0, stream>>>(xb, w1b, w3b, pair_count, offsets, pair_token, hbuf);
    moe_ffn2<<<dim3(8, 64, 8), 512, 0, stream>>>(hbuf, w2b, pair_count, offsets, pair_token, pair_prob, out);
}